// Round 8
// baseline (2595.918 us; speedup 1.0000x reference)
//
#include <hip/hip_runtime.h>
#include <stdint.h>

typedef _Float16 f16;
typedef _Float16 half8 __attribute__((ext_vector_type(8)));
typedef float f32x4 __attribute__((ext_vector_type(4)));

// ---------------------------------------------------------------------------
// MoE constants: B=8, T=2048, C=1024, H=4096, E=8, K=2, CAP=320
// tokens M=16384, expert slots = 20480, rows/expert = 2560
// Router: plain-f16 pipeline + fused logits epilogue (partial stores, no
// atomics); tokens with sorted logit gap l(2)-l(3) < THETA get exact
// (f16x3 split, split-K atomic) recompute -> top-2 SET / cumsum exact.
// GEMM: m97-faithful 128x128 tile, BK=32, 4 waves, single-buffer LDS,
// __syncthreads drain, 3-4 blocks/CU (TLP covers the drain stalls).
// ---------------------------------------------------------------------------
#define NF_MAX 2048
#define THETA  0.02f

__device__ __forceinline__ void gload16(const void* g, void* l) {
  __builtin_amdgcn_global_load_lds(
      (const __attribute__((address_space(1))) void*)g,
      (__attribute__((address_space(3))) void*)l, 16, 0, 0);
}

// ---------------------------------------------------------------------------
// 128x128-tile f16 MFMA GEMM (m97 structure). BK=32, 4 waves (2Mx2N),
// per-wave 64x64 output (4x4 16x16 frags). LDS 16KB single-buffered:
// chunk layout = 8 m-tiles x 512 f16; gload_lds writes lane*16B linear,
// source lane decode (row=lane&15, k8=lane>>4) makes ds_read at lane*8
// deliver exact MFMA fragments (refcheck-proven in rounds 1-7).
//  A: [M][lda] f16 row-major (optional rowsrcA indirection; <0 -> zeroPage).
//  B N-major: [N][ldb] f16. Split-K: grid.z chunks of Kd, k0 = z*Kd.
//  SPLIT3: A=A0+2^-12*A1, B=B0+2^-12*B1 (lo pre-scaled x4096); 3 K-passes
//          loA*hiB, hiA*loB, (scale acc 2^-12), hiA*hiB -> fp32-class.
//  EPI: 0 relu + f16 store (oH)
//       1 bias + f16 store, no relu (oH)
//       2 fused logits: relu, dot w3[4096][8], 16-lane shfl reduce, plain
//         store partial -> oLog[(n0>>7)*2+wn][row][8] (row stride = ldo)
//       3 raw f32 atomicAdd partials into oAcc (no bias)
//  nfp: blocks with m0 >= pad128(min(*nfp,NF_MAX)) exit immediately.
// ---------------------------------------------------------------------------
template<int EPI, bool SPLIT3>
__launch_bounds__(256, 4)
__global__ void gemm128(const f16* __restrict__ A0, const f16* __restrict__ A1,
                        const f16* __restrict__ B0, const f16* __restrict__ B1,
                        int N, int Kd, int lda, int ldb,
                        const int* __restrict__ rowsrcA, const f16* __restrict__ zeroPage,
                        const float* __restrict__ bias, int bias_stride, int rows_per_exp,
                        f16* __restrict__ oH, int ldo, float* __restrict__ oAcc,
                        const float* __restrict__ w3, float* __restrict__ oLog,
                        const int* __restrict__ nfp)
{
  __shared__ f16 sA[4096];                    // 8 chunks x 512 f16 = 8KB
  __shared__ f16 sB[4096];

  const int lane = threadIdx.x & 63, w = threadIdx.x >> 6;  // 4 waves
  const int wm = w >> 1, wn = w & 1;          // 2 x 2 wave grid

  // XCD-aware bijective swizzle (all grids x*y %8==0)
  const int gx  = gridDim.x;
  const int nwg = gx * gridDim.y;
  const int bid = blockIdx.y * gx + blockIdx.x;
  const int swz = (bid & 7) * (nwg >> 3) + (bid >> 3);
  const int by  = swz / gx, bx = swz - by * gx;
  const int m0  = by * 128, n0 = bx * 128;
  const int k0  = blockIdx.z * Kd;            // split-K window base

  if (nfp) {                                  // recompute-path early exit
    int nf = *nfp; nf = nf < NF_MAX ? nf : NF_MAX;
    const int lim = (nf + 127) & ~127;
    if (m0 >= lim) return;
  }

  int e = 0;
  if (rows_per_exp > 0) e = m0 / rows_per_exp;
  const f16* Bh = B0 + (size_t)e * N * ldb;

  const int nk  = Kd >> 5;                    // K-steps of 32
  const int NIT = SPLIT3 ? 3 * nk : nk;

  // staging lane decode (chunk = 16 rows x 32 k)
  const int sr  = lane & 15;                  // row within 16-row tile
  const int sk8 = lane >> 4;                  // 8-f16 column (0..3)

  // per-thread fixed row offsets; wave w stages chunks {w, w+4} of A and B
  size_t aoff[2], boff[2];
  bool az[2] = { false, false };
  #pragma unroll
  for (int jj = 0; jj < 2; ++jj) {
    const int arow = m0 + (jj * 4 + w) * 16 + sr;
    if (rowsrcA) {
      const int rs = rowsrcA[arow];
      az[jj] = (rs < 0);
      aoff[jj] = az[jj] ? 0 : (size_t)rs * lda;
    } else {
      aoff[jj] = (size_t)arow * lda;
    }
    boff[jj] = (size_t)(n0 + (jj * 4 + w) * 16 + sr) * ldb;
  }

  f32x4 acc[4][4] = {};
  int kin = 0, pass = 0;

  for (int t = 0; t < NIT; ++t) {
    const f16* Ab;
    const f16* Bb;
    if (SPLIT3) {
      if (t == 2 * nk) {                      // lo-passes done: scale 2^-12
        #pragma unroll
        for (int mi = 0; mi < 4; ++mi)
          #pragma unroll
          for (int ni = 0; ni < 4; ++ni)
            acc[mi][ni] = acc[mi][ni] * 2.44140625e-4f;
      }
      Ab = (pass == 0) ? A1 : A0;
      Bb = (pass == 1) ? B1 : Bh;
    } else { Ab = A0; Bb = Bh; }
    const int kk = k0 + (kin << 5) + sk8 * 8;

    // stage 16KB (4 gload16/thread)
    #pragma unroll
    for (int jj = 0; jj < 2; ++jj) {
      const int ch = jj * 4 + w;
      gload16(az[jj] ? zeroPage : (Ab + aoff[jj] + kk), (void*)&sA[ch * 512]);
      gload16(Bb + boff[jj] + kk,                       (void*)&sB[ch * 512]);
    }
    __syncthreads();                          // drain loads (compiler vmcnt)

    half8 aF[4], bF[4];
    #pragma unroll
    for (int mi = 0; mi < 4; ++mi)
      aF[mi] = *(const half8*)&sA[(wm * 4 + mi) * 512 + lane * 8];
    #pragma unroll
    for (int ni = 0; ni < 4; ++ni)
      bF[ni] = *(const half8*)&sB[(wn * 4 + ni) * 512 + lane * 8];
    #pragma unroll
    for (int mi = 0; mi < 4; ++mi)
      #pragma unroll
      for (int ni = 0; ni < 4; ++ni)
        acc[mi][ni] = __builtin_amdgcn_mfma_f32_16x16x32_f16(
            aF[mi], bF[ni], acc[mi][ni], 0, 0, 0);
    __syncthreads();                          // before next-step overwrite

    if (++kin == nk) { kin = 0; ++pass; }
  }

  // epilogue ---------------------------------------------------------------
  float bv[4] = { 0.f, 0.f, 0.f, 0.f };
  if (bias) {
    #pragma unroll
    for (int ni = 0; ni < 4; ++ni) {
      const int col = n0 + wn * 64 + ni * 16 + (lane & 15);
      bv[ni] = bias[(size_t)e * bias_stride + col];
    }
  }

  if (EPI == 2) {
    f32x4 wlo[4], whi[4];
    #pragma unroll
    for (int ni = 0; ni < 4; ++ni) {
      const int col = n0 + wn * 64 + ni * 16 + (lane & 15);
      wlo[ni] = *(const f32x4*)(w3 + (size_t)col * 8);
      whi[ni] = *(const f32x4*)(w3 + (size_t)col * 8 + 4);
    }
    const int p = (n0 >> 7) * 2 + wn;           // 0..63, private slot
    #pragma unroll
    for (int mi = 0; mi < 4; ++mi) {
      #pragma unroll
      for (int r = 0; r < 4; ++r) {
        const int row = m0 + wm * 64 + mi * 16 + (lane >> 4) * 4 + r;
        f32x4 plo = {}, phi = {};
        #pragma unroll
        for (int ni = 0; ni < 4; ++ni) {
          const float v = fmaxf(acc[mi][ni][r] + bv[ni], 0.f);
          plo += v * wlo[ni];
          phi += v * whi[ni];
        }
        #pragma unroll
        for (int msk = 1; msk < 16; msk <<= 1) {
          #pragma unroll
          for (int q = 0; q < 4; ++q) {
            plo[q] += __shfl_xor(plo[q], msk);
            phi[q] += __shfl_xor(phi[q], msk);
          }
        }
        if ((lane & 15) == 0) {
          float* dst = oLog + ((size_t)p * ldo + row) * 8;
          *(f32x4*)dst = plo;
          *(f32x4*)(dst + 4) = phi;
        }
      }
    }
  } else {
    #pragma unroll
    for (int mi = 0; mi < 4; ++mi) {
      #pragma unroll
      for (int r = 0; r < 4; ++r) {
        const int row = m0 + wm * 64 + mi * 16 + (lane >> 4) * 4 + r;
        #pragma unroll
        for (int ni = 0; ni < 4; ++ni) {
          const int col = n0 + wn * 64 + ni * 16 + (lane & 15);
          if (EPI == 3) {
            atomicAdd(&oAcc[(size_t)row * ldo + col], acc[mi][ni][r]);
          } else {
            float v = acc[mi][ni][r] + bv[ni];
            if (EPI == 0) v = fmaxf(v, 0.f);
            oH[(size_t)row * ldo + col] = (f16)v;
          }
        }
      }
    }
  }
}

// ---------------------------------------------------------------------------
// x (f32) -> hi f16 + lo f16 (x4096), 8 elems/thread
// ---------------------------------------------------------------------------
__global__ void split_x(const float* __restrict__ x, f16* __restrict__ hi,
                        f16* __restrict__ lo, int n)
{
  const int i = blockIdx.x * 256 + threadIdx.x;
  if (i * 8 >= n) return;
  const f32x4 a = ((const f32x4*)x)[2 * i];
  const f32x4 b = ((const f32x4*)x)[2 * i + 1];
  half8 h, l;
  #pragma unroll
  for (int j = 0; j < 4; ++j) {
    float v = a[j]; f16 hh = (f16)v;
    h[j] = hh; l[j] = (f16)((v - (float)hh) * 4096.0f);
    v = b[j]; hh = (f16)v;
    h[4 + j] = hh; l[4 + j] = (f16)((v - (float)hh) * 4096.0f);
  }
  ((half8*)hi)[i] = h;
  ((half8*)lo)[i] = l;
}

// ---------------------------------------------------------------------------
// Transpose-convert: in f32 [R][Cc] -> out f16 [Cc][R] (optional split lo)
// ---------------------------------------------------------------------------
template<bool SPLIT>
__global__ void transpose_conv(const float* __restrict__ in, f16* __restrict__ oh,
                               f16* __restrict__ ol, int R, int Cc)
{
  __shared__ float tile[64][65];
  const size_t boff = (size_t)blockIdx.z * R * Cc;
  in += boff; oh += boff;
  if (SPLIT) ol += boff;
  const int c0 = blockIdx.x * 64, r0 = blockIdx.y * 64;
  #pragma unroll
  for (int i = 0; i < 16; ++i) {
    const int idx = i * 256 + threadIdx.x;
    const int r = idx >> 6, c = idx & 63;
    tile[r][c] = in[(size_t)(r0 + r) * Cc + (c0 + c)];
  }
  __syncthreads();
  #pragma unroll
  for (int i = 0; i < 16; ++i) {
    const int idx = i * 256 + threadIdx.x;
    const int ro = idx >> 6, co = idx & 63;
    const float v = tile[co][ro];
    const f16 h = (f16)v;
    const size_t o = (size_t)(c0 + ro) * R + (r0 + co);
    oh[o] = h;
    if (SPLIT) ol[o] = (f16)((v - (float)h) * 4096.0f);
  }
}

// ---------------------------------------------------------------------------
// softmax + top-2 + margin flagging; sums 64 per-(block,wave) partials
// ---------------------------------------------------------------------------
__global__ void topk_flag(const float* __restrict__ part, const float* __restrict__ b3,
                          int* __restrict__ eidx, float* __restrict__ gval,
                          int* __restrict__ flags, int* __restrict__ nfc)
{
  const int t = blockIdx.x * 256 + threadIdx.x;     // 0..16383
  float l[8];
  #pragma unroll
  for (int e = 0; e < 8; ++e) l[e] = b3[e];
  for (int p = 0; p < 64; ++p) {
    const float* src = part + ((size_t)p * 16384 + t) * 8;
    const f32x4 a = *(const f32x4*)src;
    const f32x4 b = *(const f32x4*)(src + 4);
    #pragma unroll
    for (int q = 0; q < 4; ++q) { l[q] += a[q]; l[4 + q] += b[q]; }
  }
  float mx = l[0];
  #pragma unroll
  for (int e = 1; e < 8; ++e) mx = fmaxf(mx, l[e]);
  float ex[8], s = 0.f;
  #pragma unroll
  for (int e = 0; e < 8; ++e) { ex[e] = expf(l[e] - mx); s += ex[e]; }
  float p1 = -1.f, p2 = -1.f; int e1 = 0, e2 = 0;
  #pragma unroll
  for (int e = 0; e < 8; ++e) {               // strict '>' = lax.top_k tie-break
    const float pe = ex[e] / s;
    if (pe > p1)      { p2 = p1; e2 = e1; p1 = pe; e1 = e; }
    else if (pe > p2) { p2 = pe; e2 = e; }
  }
  eidx[t * 2] = e1; eidx[t * 2 + 1] = e2;
  gval[t * 2] = p1; gval[t * 2 + 1] = p2;
  // sorted-logit top-3 gap -> flag for exact recompute
  float l1 = -1e30f, l2 = -1e30f, l3 = -1e30f;
  #pragma unroll
  for (int e = 0; e < 8; ++e) {
    const float le = l[e];
    if (le > l1)      { l3 = l2; l2 = l1; l1 = le; }
    else if (le > l2) { l3 = l2; l2 = le; }
    else if (le > l3) { l3 = le; }
  }
  if (l2 - l3 < THETA) {
    const int s0 = atomicAdd(nfc, 1);
    if (s0 < NF_MAX) flags[s0] = t;
  }
}

// ---------------------------------------------------------------------------
// relu(h1r + b1) -> split f16 hi/lo  (recompute path, rows < pad(nf))
// ---------------------------------------------------------------------------
__global__ void post1(const float* __restrict__ h1r, const float* __restrict__ b1,
                      f16* __restrict__ hh, f16* __restrict__ hl,
                      const int* __restrict__ nfc)
{
  int nf = *nfc; nf = nf < NF_MAX ? nf : NF_MAX;
  const int lim = (nf + 255) & ~255;
  const int row = blockIdx.x;
  if (row >= lim) return;
  const int j = blockIdx.y * 2048 + threadIdx.x * 8;
  const float* src = h1r + (size_t)row * 4096 + j;
  const f32x4 a = *(const f32x4*)src;
  const f32x4 b = *(const f32x4*)(src + 4);
  half8 h, l;
  #pragma unroll
  for (int k = 0; k < 4; ++k) {
    float v = fmaxf(a[k] + b1[j + k], 0.f);
    f16 x = (f16)v; h[k] = x; l[k] = (f16)((v - (float)x) * 4096.0f);
    v = fmaxf(b[k] + b1[j + 4 + k], 0.f);
    x = (f16)v; h[4 + k] = x; l[4 + k] = (f16)((v - (float)x) * 4096.0f);
  }
  *(half8*)(hh + (size_t)row * 4096 + j) = h;
  *(half8*)(hl + (size_t)row * 4096 + j) = l;
}

// ---------------------------------------------------------------------------
// EXACT logits for flagged tokens from f32 h2r (+b2, relu), f64 accumulate
// ---------------------------------------------------------------------------
__global__ void logits_exact(const float* __restrict__ h2r, const float* __restrict__ b2,
                             const float* __restrict__ w3, const float* __restrict__ b3,
                             const int* __restrict__ flags, const int* __restrict__ nfc,
                             int* __restrict__ eidx, float* __restrict__ gval)
{
  const int srow = blockIdx.x;
  int nf = *nfc; nf = nf < NF_MAX ? nf : NF_MAX;
  if (srow >= nf) return;
  const float* hrow = h2r + (size_t)srow * 4096;
  double p[8];
  #pragma unroll
  for (int e = 0; e < 8; ++e) p[e] = 0.0;
  for (int i = 0; i < 16; ++i) {
    const int k = i * 256 + threadIdx.x;
    const double h = (double)fmaxf(hrow[k] + b2[k], 0.f);
    const float* wp = w3 + (size_t)k * 8;
    #pragma unroll
    for (int e = 0; e < 8; ++e) p[e] += h * (double)wp[e];
  }
  #pragma unroll
  for (int e = 0; e < 8; ++e)
    for (int off = 32; off > 0; off >>= 1)
      p[e] += __shfl_down(p[e], off);
  __shared__ double sp[4][8];
  const int lane = threadIdx.x & 63, wv = threadIdx.x >> 6;
  if (lane == 0) {
    #pragma unroll
    for (int e = 0; e < 8; ++e) sp[wv][e] = p[e];
  }
  __syncthreads();
  if (threadIdx.x == 0) {
    float l[8];
    #pragma unroll
    for (int e = 0; e < 8; ++e)
      l[e] = (float)(sp[0][e] + sp[1][e] + sp[2][e] + sp[3][e] + (double)b3[e]);
    float mx = l[0];
    for (int e = 1; e < 8; ++e) mx = fmaxf(mx, l[e]);
    float ex[8], s = 0.f;
    for (int e = 0; e < 8; ++e) { ex[e] = expf(l[e] - mx); s += ex[e]; }
    float p1 = -1.f, p2 = -1.f; int e1 = 0, e2 = 0;
    for (int e = 0; e < 8; ++e) {
      const float pe = ex[e] / s;
      if (pe > p1)      { p2 = p1; e2 = e1; p1 = pe; e1 = e; }
      else if (pe > p2) { p2 = pe; e2 = e; }
    }
    const int tok = flags[srow];
    eidx[tok * 2] = e1; eidx[tok * 2 + 1] = e2;
    gval[tok * 2] = p1; gval[tok * 2 + 1] = p2;
  }
}

// ---------------------------------------------------------------------------
// FCFS capacity scan: one wave per (expert, batch-row); exact cumsum semantics.
// Builds rowsrc (slot->token, FULLY initialized incl. -1 tail) and tokslot.
// ---------------------------------------------------------------------------
__global__ void route_scan(const int* __restrict__ eidx, const float* __restrict__ gval,
                           int* __restrict__ cnt, int* __restrict__ rowsrc,
                           int* __restrict__ tokslot)
{
  const int pair = blockIdx.x;            // e*8 + b
  const int e = pair >> 3, b = pair & 7;
  const int lane = threadIdx.x;           // blockDim = 64
  int running = 0;
  for (int t0 = 0; t0 < 2048; t0 += 64) {
    const int t = t0 + lane;
    const int i2 = (b * 2048 + t) * 2;
    const int m0 = (eidx[i2] == e), m1 = (eidx[i2 + 1] == e);
    const int m = m0 | m1;
    const unsigned long long bal = __ballot(m);
    const int pos = running + __popcll(bal & ((1ull << lane) - 1ull));
    if (m && pos < 320) {
      const int slot = pair * 320 + pos;
      rowsrc[slot] = b * 2048 + t;
      tokslot[(b * 2048 + t) * 2 + (m0 ? 0 : 1)] = slot;
    }
    running += __popcll(bal);
  }
  const int c = running < 320 ? running : 320;
  for (int s = c + lane; s < 320; s += 64) rowsrc[pair * 320 + s] = -1;
  if (lane == 0) cnt[pair] = c;
}

// ---------------------------------------------------------------------------
// Combine: out[token] = sum_j gate_j * yb[slot_j]  (bias already in yb)
// ---------------------------------------------------------------------------
__global__ void combine(const f16* __restrict__ yb, const int* __restrict__ tokslot,
                        const float* __restrict__ gval, float* __restrict__ out)
{
  const int t = blockIdx.x;
  const int s0 = tokslot[t * 2], s1 = tokslot[t * 2 + 1];
  const float g0 = gval[t * 2], g1 = gval[t * 2 + 1];
  float a[8] = {};
  if (s0 >= 0) {
    const half8 y = ((const half8*)(yb + (size_t)s0 * 1024))[threadIdx.x];
    #pragma unroll
    for (int k = 0; k < 8; ++k) a[k] += g0 * (float)y[k];
  }
  if (s1 >= 0) {
    const half8 y = ((const half8*)(yb + (size_t)s1 * 1024))[threadIdx.x];
    #pragma unroll
    for (int k = 0; k < 8; ++k) a[k] += g1 * (float)y[k];
  }
  float* dst = out + (size_t)t * 1024 + threadIdx.x * 8;
  f32x4 lo = { a[0], a[1], a[2], a[3] }, hi = { a[4], a[5], a[6], a[7] };
  *(f32x4*)dst = lo;
  *(f32x4*)(dst + 4) = hi;
}

// ---------------------------------------------------------------------------
extern "C" void kernel_launch(void* const* d_in, const int* in_sizes, int n_in,
                              void* d_out, int out_size, void* d_ws, size_t ws_size,
                              hipStream_t stream)
{
  (void)in_sizes; (void)n_in; (void)out_size;
  const float* x   = (const float*)d_in[0];
  const float* rw1 = (const float*)d_in[1];
  const float* rb1 = (const float*)d_in[2];
  const float* rw2 = (const float*)d_in[3];
  const float* rb2 = (const float*)d_in[4];
  const float* rw3 = (const float*)d_in[5];
  const float* rb3 = (const float*)d_in[6];
  const float* ew1 = (const float*)d_in[7];
  const float* eb1 = (const float*)d_in[8];
  const float* ew2 = (const float*)d_in[9];
  const float* eb2 = (const float*)d_in[10];

  constexpr size_t MB = 1024ull * 1024ull;
  constexpr size_t KB = 1024ull;
  char* ws = (char*)d_ws;
  if (ws_size < 401 * MB) return;   // need 401 MB of scratch

  // --- region 0..128 MB: router phase = h1f [16384][4096] f16;
  //     expert phase = ew1t(64) + ew2t(64)  (transposes run after router)
  f16*   h1f  = (f16*)(ws);
  f16*   ew1t = (f16*)(ws);
  f16*   ew2t = (f16*)(ws + 64 * MB);
  // --- persistent
  f16*   xhi  = (f16*)(ws + 128 * MB);               // 32MB [16384][1024]
  char*  S    = ws + 160 * MB;                       // small arrays (1MB)
  int*   eidx   = (int*)(S);                         // 128KB
  float* gval   = (float*)(S + 128 * KB);            // 128KB
  int*   cnt    = (int*)(S + 256 * KB);              // 256B
  int*   nfc    = (int*)(S + 260 * KB);              // 4B
  int*   flags  = (int*)(S + 264 * KB);              // 8KB
  int*   tokslot= (int*)(S + 272 * KB);              // 128KB
  int*   rowsrc = (int*)(S + 400 * KB);              // 80KB
  f16*   zeros  = (f16*)(S + 480 * KB);              // 16KB
  // --- router phase (161..305)
  f16*   xlo    = (f16*)(ws + 161 * MB);             // 32MB
  f16*   rw1thi = (f16*)(ws + 193 * MB);             // 8MB  [H][C]
  f16*   rw1tlo = (f16*)(ws + 201 * MB);             // 8MB
  f16*   rw2thi = (f16*)(ws + 209 * MB);             // 32MB [H][H]
  f16*   rw2tlo = (f16*)(ws + 241 * MB);             // 32MB
  float* part   = (float*)(ws + 273 * MB);           // 32MB [64][16384][8]
  // --- recompute (305..401; xlo/rw*t still live; part dead)
  float* h1r    = (float*)(ws + 305 * MB);           // 32MB [2048][4096] f32
  float* h2r    = (float*)(ws + 337 * MB);           // 32MB
  f16*   h1rh   = (f16*)(ws + 369 * MB);             // 16MB
  f16*   h1rl   = (f16*)(ws + 385 * MB);             // 16MB -> 401
  // --- expert phase (everything above 161 dead)
  f16*   h_e    = (f16*)(ws + 161 * MB);             // 160MB [20480][4096]
  f16*   yb     = (f16*)(ws + 321 * MB);             // 40MB  [20480][1024]

  // init
  hipMemsetAsync(nfc, 0, 4, stream);
  hipMemsetAsync(tokslot, 0xFF, 128 * KB, stream);
  hipMemsetAsync(zeros, 0, 16 * KB, stream);
  hipMemsetAsync(h1r, 0, 64 * MB, stream);           // h1r+h2r contiguous

  // conversions / splits (router weights only; expert weights later)
  split_x<<<8192, 256, 0, stream>>>(x, xhi, xlo, 16384 * 1024);
  transpose_conv<true ><<<dim3(64, 16, 1), 256, 0, stream>>>(rw1, rw1thi, rw1tlo, 1024, 4096);
  transpose_conv<true ><<<dim3(64, 64, 1), 256, 0, stream>>>(rw2, rw2thi, rw2tlo, 4096, 4096);

  // FAST router: plain f16, ALL 16384 tokens in one pass
  gemm128<0, false><<<dim3(32, 128), 256, 0, stream>>>(
      xhi, nullptr, rw1thi, nullptr, 4096, 1024, 1024, 1024,
      nullptr, nullptr, rb1, 0, 0,
      h1f, 4096, nullptr, nullptr, nullptr, nullptr);
  gemm128<2, false><<<dim3(32, 128), 256, 0, stream>>>(
      h1f, nullptr, rw2thi, nullptr, 4096, 4096, 4096, 4096,
      nullptr, nullptr, rb2, 0, 0,
      nullptr, 16384, nullptr, rw3, part, nullptr);
  topk_flag<<<64, 256, 0, stream>>>(part, rb3, eidx, gval, flags, nfc);

  // EXACT recompute for flagged tokens (split-K f32-atomic, f16x3 split)
  gemm128<3, true><<<dim3(32, 16, 2), 256, 0, stream>>>(
      xhi, xlo, rw1thi, rw1tlo, 4096, 512, 1024, 1024,
      flags, zeros, nullptr, 0, 0,
      nullptr, 4096, h1r, nullptr, nullptr, nfc);
  post1<<<dim3(2048, 2), 256, 0, stream>>>(h1r, rb1, h1rh, h1rl, nfc);
  gemm128<3, true><<<dim3(32, 16, 4), 256, 0, stream>>>(
      h1rh, h1rl, rw2thi, rw2tlo, 4096, 1024, 4096, 4096,
      nullptr, nullptr, nullptr, 0, 0,
      nullptr, 4096, h2r, nullptr, nullptr, nfc);
  logits_exact<<<NF_MAX, 256, 0, stream>>>(h2r, rb2, rw3, rb3, flags, nfc,
                                           eidx, gval);

  // dispatch maps
  route_scan<<<64, 64, 0, stream>>>(eidx, gval, cnt, rowsrc, tokslot);

  // expert weight conversion (h1f region now dead)
  transpose_conv<false><<<dim3(64, 16, 8), 256, 0, stream>>>(ew1, ew1t, nullptr, 1024, 4096);
  transpose_conv<false><<<dim3(16, 64, 8), 256, 0, stream>>>(ew2, ew2t, nullptr, 4096, 1024);

  // experts: A-rows gathered by indirection from xhi (zero page for empties)
  gemm128<0, false><<<dim3(32, 160), 256, 0, stream>>>(
      xhi, nullptr, ew1t, nullptr, 4096, 1024, 1024, 1024,
      rowsrc, zeros, eb1, 4096, 2560,
      h_e, 4096, nullptr, nullptr, nullptr, nullptr);
  gemm128<1, false><<<dim3(8, 160), 256, 0, stream>>>(
      h_e, nullptr, ew2t, nullptr, 1024, 4096, 4096, 4096,
      nullptr, nullptr, eb2, 1024, 2560,
      yb, 1024, nullptr, nullptr, nullptr, nullptr);

  // combine: one write per output element (dropped tokens -> 0)
  combine<<<16384, 128, 0, stream>>>(yb, tokslot, gval, (float*)d_out);
}

// Round 9
// 1786.942 us; speedup vs baseline: 1.4527x; 1.4527x over previous
//
#include <hip/hip_runtime.h>
#include <stdint.h>

typedef _Float16 f16;
typedef _Float16 half8 __attribute__((ext_vector_type(8)));
typedef float f32x4 __attribute__((ext_vector_type(4)));

// ---------------------------------------------------------------------------
// MoE constants: B=8, T=2048, C=1024, H=4096, E=8, K=2, CAP=320
// tokens M=16384, expert slots = 20480, rows/expert = 2560
// Router: plain-f16 pipeline + fused logits epilogue (partial stores, no
// atomics); tokens with sorted logit gap l(2)-l(3) < THETA get exact
// (f16x3 split, split-K atomic) recompute -> top-2 SET / cumsum exact.
// GEMM: 256x256 tile, BK=64, 8 waves, 4-phase pipelined K-loop (round-4
// form: reads split 8/4, stageA/stageB in separate phases, counted vmcnt(8)
// twice per K-tile — the 963-TF-measured schedule; hoist/merge variants
// measured 821-840 and were reverted).
// ---------------------------------------------------------------------------
#define NF_MAX 2048
#define THETA  0.02f

__device__ __forceinline__ void gload16(const void* g, void* l) {
  __builtin_amdgcn_global_load_lds(
      (const __attribute__((address_space(1))) void*)g,
      (__attribute__((address_space(3))) void*)l, 16, 0, 0);
}

#define BAR() do { __builtin_amdgcn_s_barrier(); __builtin_amdgcn_sched_barrier(0); } while (0)
#define WAIT_VM8() do { asm volatile("s_waitcnt vmcnt(8)" ::: "memory"); __builtin_amdgcn_sched_barrier(0); } while (0)
#define WAIT_VM0() do { asm volatile("s_waitcnt vmcnt(0)" ::: "memory"); __builtin_amdgcn_sched_barrier(0); } while (0)

// ---------------------------------------------------------------------------
// 256x256-tile f16 MFMA GEMM, 8 waves (2Mx4N), BK=64, 4-phase pipelined
// K-loop. Ring of 4 kc-half slots per operand (slot = 256 rows x 32 k,
// fragment-major chunks -> conflict-free lane-linear ds_read_b128).
// Phase p0: 8 frag reads (A mh0 + B) of slot sa0; stage A(t+1,kc1).
// Phase p1: 4 frag reads (A mh1); stage B(t+1,kc1); vmcnt(8) -> slot sa0^2
//           (t,kc1... i.e. next-consumed slot) verified complete; barrier.
// p2/p3 mirror for kc1, staging (t+2,kc0) into the just-freed slot.
// Race-free: stage target slot was fully consumed one phase-pair earlier;
// vmcnt(8)+barrier proves the next-consumed slot landed (12 max in flight,
// oldest 4 = that slot's A+B).
//  A: [M][lda] f16 row-major (optional rowsrcA indirection; <0 -> zeroPage).
//  B N-major: [N][ldb] f16. Split-K: grid.z chunks of Kd, k0 = z*Kd.
//  SPLIT3: A=A0+2^-12*A1, B=B0+2^-12*B1 (lo pre-scaled x4096); 3 K-passes.
//  EPI: 0 relu + f16 store (oH)
//       1 bias + f16 store, no relu (oH)
//       2 fused logits: relu, dot w3[4096][8], 16-lane shfl reduce, plain
//         store partial -> oLog[(n0>>8)*4+wn][row][8] (row stride = ldo)
//       3 raw f32 atomicAdd partials into oAcc (no bias)
//  nfp: blocks with m0 >= pad256(min(*nfp,NF_MAX)) exit immediately.
// ---------------------------------------------------------------------------
template<int EPI, bool SPLIT3>
__launch_bounds__(512, 2)
__global__ void gemm256(const f16* __restrict__ A0, const f16* __restrict__ A1,
                        const f16* __restrict__ B0, const f16* __restrict__ B1,
                        int N, int Kd, int lda, int ldb,
                        const int* __restrict__ rowsrcA, const f16* __restrict__ zeroPage,
                        const float* __restrict__ bias, int bias_stride, int rows_per_exp,
                        f16* __restrict__ oH, int ldo, float* __restrict__ oAcc,
                        const float* __restrict__ w3, float* __restrict__ oLog,
                        const int* __restrict__ nfp)
{
  __shared__ f16 lds[4 * 8192 * 2 + 512];     // A ring | B ring | 1KB dummy
  f16* sA = lds;
  f16* sB = lds + 4 * 8192;
  f16* sDummy = lds + 8 * 8192;

  const int tid  = threadIdx.x;
  const int lane = tid & 63, w = tid >> 6;    // 8 waves
  const int wm = w >> 2, wn = w & 3;          // 2 x 4 wave grid

  // XCD-aware bijective swizzle over x*y (all grids %8==0)
  const int gx  = gridDim.x;
  const int nwg = gx * gridDim.y;
  const int bid = blockIdx.y * gx + blockIdx.x;
  const int swz = (bid & 7) * (nwg >> 3) + (bid >> 3);
  const int by  = swz / gx, bx = swz - by * gx;
  const int m0  = by * 256, n0 = bx * 256;
  const int k0  = blockIdx.z * Kd;            // split-K window base

  if (nfp) {                                  // recompute-path early exit
    int nf = *nfp; nf = nf < NF_MAX ? nf : NF_MAX;
    const int lim = (nf + 255) & ~255;
    if (m0 >= lim) return;
  }

  int e = 0;
  if (rows_per_exp > 0) e = m0 / rows_per_exp;
  const f16* Bh = B0 + (size_t)e * N * ldb;

  const int nk  = Kd >> 6;
  const int NIT = SPLIT3 ? 3 * nk : nk;

  // staging lane decode
  const int sr  = lane & 15;                  // row within 16-row tile
  const int sk8 = lane >> 4;                  // 16B column within 32-col half

  // per-thread fixed row offsets (A may be indirect)
  size_t aoff[2], boff[2];
  bool az[2] = { false, false };
  #pragma unroll
  for (int jj = 0; jj < 2; ++jj) {
    const int arow = m0 + (jj * 8 + w) * 16 + sr;
    if (rowsrcA) {
      const int rs = rowsrcA[arow];
      az[jj] = (rs < 0);
      aoff[jj] = az[jj] ? 0 : (size_t)rs * lda;
    } else {
      aoff[jj] = (size_t)arow * lda;
    }
    boff[jj] = (size_t)(n0 + (jj * 8 + w) * 16 + sr) * ldb;
  }

  auto stageA = [&](const f16* base, int kk, int kc, f16* slotBase, bool valid) {
    #pragma unroll
    for (int jj = 0; jj < 2; ++jj) {
      const int mt = jj * 8 + w;
      f16* dst = valid ? (slotBase + mt * 512) : sDummy;
      const f16* src = az[jj] ? zeroPage
                              : base + aoff[jj] + (k0 + kk + kc * 32 + sk8 * 8);
      gload16(src, dst);
    }
  };
  auto stageB = [&](const f16* base, int kk, int kc, f16* slotBase, bool valid) {
    #pragma unroll
    for (int jj = 0; jj < 2; ++jj) {
      const int mt = jj * 8 + w;
      f16* dst = valid ? (slotBase + mt * 512) : sDummy;
      const f16* src = base + boff[jj] + (k0 + kk + kc * 32 + sk8 * 8);
      gload16(src, dst);
    }
  };

  struct It { const f16* Ab; const f16* Bb; int kk, kin, pass; };
  const f16* Ab0 = SPLIT3 ? A1 : A0;
  auto advance = [&](It& s) {
    if (s.kin + 1 < nk) { s.kin++; }
    else if (SPLIT3 && s.pass < 2) {
      s.kin = 0; s.pass++;
      s.Ab = (s.pass == 0) ? A1 : A0;
      s.Bb = (s.pass == 1) ? B1 : Bh;
    } // else saturate (dest is dummy anyway)
    s.kk = s.kin << 6;
  };
  It it1 = { Ab0, Bh, 64, 1, 0 };             // j = t+1
  It it2 = { Ab0, Bh, 128, 2, 0 };            // j = t+2

  // prologue: stage (0,kc0)A/B, (0,kc1)A/B, (1,kc0)A/B -> slots 0,1,2
  stageA(Ab0, 0, 0, &sA[0], true);
  stageB(Bh,  0, 0, &sB[0], true);
  stageA(Ab0, 0, 1, &sA[8192], true);
  stageB(Bh,  0, 1, &sB[8192], true);
  stageA(it1.Ab, it1.kk, 0, &sA[2 * 8192], true);
  stageB(it1.Bb, it1.kk, 0, &sB[2 * 8192], true);
  WAIT_VM8();
  BAR();

  f32x4 acc[8][4] = {};
  const int aBase = wm * 8;
  const int bBase = wn * 4;

  auto mfma16 = [&](half8* af, half8* bf, int moff) {
    __builtin_amdgcn_s_setprio(1);
    #pragma unroll
    for (int mi = 0; mi < 4; ++mi)
      #pragma unroll
      for (int ni = 0; ni < 4; ++ni)
        acc[moff + mi][ni] = __builtin_amdgcn_mfma_f32_16x16x32_f16(
            af[mi], bf[ni], acc[moff + mi][ni], 0, 0, 0);
    __builtin_amdgcn_s_setprio(0);
  };
  auto rdA = [&](half8* dst, int slot, int mtb) {
    #pragma unroll
    for (int mi = 0; mi < 4; ++mi)
      dst[mi] = *(const half8*)&sA[slot * 8192 + (mtb + mi) * 512 + lane * 8];
  };
  auto rdB = [&](half8* dst, int slot) {
    #pragma unroll
    for (int ni = 0; ni < 4; ++ni)
      dst[ni] = *(const half8*)&sB[slot * 8192 + (bBase + ni) * 512 + lane * 8];
  };

  for (int t = 0; t < NIT; ++t) {
    const int sa0 = (2 * t) & 3, sa1 = sa0 ^ 1;
    const bool v1 = (t + 1 < NIT), v2 = (t + 2 < NIT);

    if (SPLIT3 && t == 2 * nk) {              // lo-passes done: scale 2^-12
      #pragma unroll
      for (int mi = 0; mi < 8; ++mi)
        #pragma unroll
        for (int ni = 0; ni < 4; ++ni)
          acc[mi][ni] = acc[mi][ni] * 2.44140625e-4f;
    }

    half8 aF[4], bF[4], aG[4];

    // p0: read A(mh0,kc0)+B(kc0); stage (t+1,kc1)A -> slot sa0^3
    rdA(aF, sa0, aBase);
    rdB(bF, sa0);
    stageA(it1.Ab, it1.kk, 1, &sA[(sa0 ^ 3) * 8192], v1);
    BAR();
    mfma16(aF, bF, 0);
    BAR();

    // p1: read A(mh1,kc0); stage (t+1,kc1)B; vmcnt(8) covers (t,kc1)
    rdA(aG, sa0, aBase + 4);
    stageB(it1.Bb, it1.kk, 1, &sB[(sa0 ^ 3) * 8192], v1);
    WAIT_VM8();
    BAR();
    mfma16(aG, bF, 4);
    BAR();

    // p2: read A(mh0,kc1)+B(kc1); stage (t+2,kc0)A -> slot sa0 (now dead)
    rdA(aF, sa1, aBase);
    rdB(bF, sa1);
    stageA(it2.Ab, it2.kk, 0, &sA[sa0 * 8192], v2);
    BAR();
    mfma16(aF, bF, 0);
    BAR();

    // p3: read A(mh1,kc1); stage (t+2,kc0)B; vmcnt(8) covers (t+1,kc0)
    rdA(aG, sa1, aBase + 4);
    stageB(it2.Bb, it2.kk, 0, &sB[sa0 * 8192], v2);
    WAIT_VM8();
    BAR();
    mfma16(aG, bF, 4);
    BAR();

    it1 = it2;
    advance(it2);
  }
  WAIT_VM0();   // drain tail (dummy) loads before LDS is released

  // epilogue ---------------------------------------------------------------
  float bv[4] = { 0.f, 0.f, 0.f, 0.f };
  if (bias) {
    #pragma unroll
    for (int ni = 0; ni < 4; ++ni) {
      const int col = n0 + wn * 64 + ni * 16 + (lane & 15);
      bv[ni] = bias[(size_t)e * bias_stride + col];
    }
  }

  if (EPI == 2) {
    f32x4 wlo[4], whi[4];
    #pragma unroll
    for (int ni = 0; ni < 4; ++ni) {
      const int col = n0 + wn * 64 + ni * 16 + (lane & 15);
      wlo[ni] = *(const f32x4*)(w3 + (size_t)col * 8);
      whi[ni] = *(const f32x4*)(w3 + (size_t)col * 8 + 4);
    }
    const int p = (n0 >> 8) * 4 + wn;           // 0..63, private slot
    #pragma unroll
    for (int mi = 0; mi < 8; ++mi) {
      #pragma unroll
      for (int r = 0; r < 4; ++r) {
        const int row = m0 + wm * 128 + mi * 16 + (lane >> 4) * 4 + r;
        f32x4 plo = {}, phi = {};
        #pragma unroll
        for (int ni = 0; ni < 4; ++ni) {
          const float v = fmaxf(acc[mi][ni][r] + bv[ni], 0.f);
          plo += v * wlo[ni];
          phi += v * whi[ni];
        }
        #pragma unroll
        for (int msk = 1; msk < 16; msk <<= 1) {
          #pragma unroll
          for (int q = 0; q < 4; ++q) {
            plo[q] += __shfl_xor(plo[q], msk);
            phi[q] += __shfl_xor(phi[q], msk);
          }
        }
        if ((lane & 15) == 0) {
          float* dst = oLog + ((size_t)p * ldo + row) * 8;
          *(f32x4*)dst = plo;
          *(f32x4*)(dst + 4) = phi;
        }
      }
    }
  } else {
    #pragma unroll
    for (int mi = 0; mi < 8; ++mi) {
      #pragma unroll
      for (int r = 0; r < 4; ++r) {
        const int row = m0 + wm * 128 + mi * 16 + (lane >> 4) * 4 + r;
        #pragma unroll
        for (int ni = 0; ni < 4; ++ni) {
          const int col = n0 + wn * 64 + ni * 16 + (lane & 15);
          if (EPI == 3) {
            atomicAdd(&oAcc[(size_t)row * ldo + col], acc[mi][ni][r]);
          } else {
            float v = acc[mi][ni][r] + bv[ni];
            if (EPI == 0) v = fmaxf(v, 0.f);
            oH[(size_t)row * ldo + col] = (f16)v;
          }
        }
      }
    }
  }
}

// ---------------------------------------------------------------------------
// x (f32) -> hi f16 + lo f16 (x4096), 8 elems/thread
// ---------------------------------------------------------------------------
__global__ void split_x(const float* __restrict__ x, f16* __restrict__ hi,
                        f16* __restrict__ lo, int n)
{
  const int i = blockIdx.x * 256 + threadIdx.x;
  if (i * 8 >= n) return;
  const f32x4 a = ((const f32x4*)x)[2 * i];
  const f32x4 b = ((const f32x4*)x)[2 * i + 1];
  half8 h, l;
  #pragma unroll
  for (int j = 0; j < 4; ++j) {
    float v = a[j]; f16 hh = (f16)v;
    h[j] = hh; l[j] = (f16)((v - (float)hh) * 4096.0f);
    v = b[j]; hh = (f16)v;
    h[4 + j] = hh; l[4 + j] = (f16)((v - (float)hh) * 4096.0f);
  }
  ((half8*)hi)[i] = h;
  ((half8*)lo)[i] = l;
}

// ---------------------------------------------------------------------------
// Transpose-convert: in f32 [R][Cc] -> out f16 [Cc][R] (optional split lo)
// ---------------------------------------------------------------------------
template<bool SPLIT>
__global__ void transpose_conv(const float* __restrict__ in, f16* __restrict__ oh,
                               f16* __restrict__ ol, int R, int Cc)
{
  __shared__ float tile[64][65];
  const size_t boff = (size_t)blockIdx.z * R * Cc;
  in += boff; oh += boff;
  if (SPLIT) ol += boff;
  const int c0 = blockIdx.x * 64, r0 = blockIdx.y * 64;
  #pragma unroll
  for (int i = 0; i < 16; ++i) {
    const int idx = i * 256 + threadIdx.x;
    const int r = idx >> 6, c = idx & 63;
    tile[r][c] = in[(size_t)(r0 + r) * Cc + (c0 + c)];
  }
  __syncthreads();
  #pragma unroll
  for (int i = 0; i < 16; ++i) {
    const int idx = i * 256 + threadIdx.x;
    const int ro = idx >> 6, co = idx & 63;
    const float v = tile[co][ro];
    const f16 h = (f16)v;
    const size_t o = (size_t)(c0 + ro) * R + (r0 + co);
    oh[o] = h;
    if (SPLIT) ol[o] = (f16)((v - (float)h) * 4096.0f);
  }
}

// ---------------------------------------------------------------------------
// softmax + top-2 + margin flagging; sums 64 per-(block,wave) partials
// ---------------------------------------------------------------------------
__global__ void topk_flag(const float* __restrict__ part, const float* __restrict__ b3,
                          int* __restrict__ eidx, float* __restrict__ gval,
                          int* __restrict__ flags, int* __restrict__ nfc)
{
  const int t = blockIdx.x * 256 + threadIdx.x;     // 0..16383
  float l[8];
  #pragma unroll
  for (int e = 0; e < 8; ++e) l[e] = b3[e];
  for (int p = 0; p < 64; ++p) {
    const float* src = part + ((size_t)p * 16384 + t) * 8;
    const f32x4 a = *(const f32x4*)src;
    const f32x4 b = *(const f32x4*)(src + 4);
    #pragma unroll
    for (int q = 0; q < 4; ++q) { l[q] += a[q]; l[4 + q] += b[q]; }
  }
  float mx = l[0];
  #pragma unroll
  for (int e = 1; e < 8; ++e) mx = fmaxf(mx, l[e]);
  float ex[8], s = 0.f;
  #pragma unroll
  for (int e = 0; e < 8; ++e) { ex[e] = expf(l[e] - mx); s += ex[e]; }
  float p1 = -1.f, p2 = -1.f; int e1 = 0, e2 = 0;
  #pragma unroll
  for (int e = 0; e < 8; ++e) {               // strict '>' = lax.top_k tie-break
    const float pe = ex[e] / s;
    if (pe > p1)      { p2 = p1; e2 = e1; p1 = pe; e1 = e; }
    else if (pe > p2) { p2 = pe; e2 = e; }
  }
  eidx[t * 2] = e1; eidx[t * 2 + 1] = e2;
  gval[t * 2] = p1; gval[t * 2 + 1] = p2;
  // sorted-logit top-3 gap -> flag for exact recompute
  float l1 = -1e30f, l2 = -1e30f, l3 = -1e30f;
  #pragma unroll
  for (int e = 0; e < 8; ++e) {
    const float le = l[e];
    if (le > l1)      { l3 = l2; l2 = l1; l1 = le; }
    else if (le > l2) { l3 = l2; l2 = le; }
    else if (le > l3) { l3 = le; }
  }
  if (l2 - l3 < THETA) {
    const int s0 = atomicAdd(nfc, 1);
    if (s0 < NF_MAX) flags[s0] = t;
  }
}

// ---------------------------------------------------------------------------
// relu(h1r + b1) -> split f16 hi/lo  (recompute path, rows < pad(nf))
// ---------------------------------------------------------------------------
__global__ void post1(const float* __restrict__ h1r, const float* __restrict__ b1,
                      f16* __restrict__ hh, f16* __restrict__ hl,
                      const int* __restrict__ nfc)
{
  int nf = *nfc; nf = nf < NF_MAX ? nf : NF_MAX;
  const int lim = (nf + 255) & ~255;
  const int row = blockIdx.x;
  if (row >= lim) return;
  const int j = blockIdx.y * 2048 + threadIdx.x * 8;
  const float* src = h1r + (size_t)row * 4096 + j;
  const f32x4 a = *(const f32x4*)src;
  const f32x4 b = *(const f32x4*)(src + 4);
  half8 h, l;
  #pragma unroll
  for (int k = 0; k < 4; ++k) {
    float v = fmaxf(a[k] + b1[j + k], 0.f);
    f16 x = (f16)v; h[k] = x; l[k] = (f16)((v - (float)x) * 4096.0f);
    v = fmaxf(b[k] + b1[j + 4 + k], 0.f);
    x = (f16)v; h[4 + k] = x; l[4 + k] = (f16)((v - (float)x) * 4096.0f);
  }
  *(half8*)(hh + (size_t)row * 4096 + j) = h;
  *(half8*)(hl + (size_t)row * 4096 + j) = l;
}

// ---------------------------------------------------------------------------
// EXACT logits for flagged tokens from f32 h2r (+b2, relu), f64 accumulate
// ---------------------------------------------------------------------------
__global__ void logits_exact(const float* __restrict__ h2r, const float* __restrict__ b2,
                             const float* __restrict__ w3, const float* __restrict__ b3,
                             const int* __restrict__ flags, const int* __restrict__ nfc,
                             int* __restrict__ eidx, float* __restrict__ gval)
{
  const int srow = blockIdx.x;
  int nf = *nfc; nf = nf < NF_MAX ? nf : NF_MAX;
  if (srow >= nf) return;
  const float* hrow = h2r + (size_t)srow * 4096;
  double p[8];
  #pragma unroll
  for (int e = 0; e < 8; ++e) p[e] = 0.0;
  for (int i = 0; i < 16; ++i) {
    const int k = i * 256 + threadIdx.x;
    const double h = (double)fmaxf(hrow[k] + b2[k], 0.f);
    const float* wp = w3 + (size_t)k * 8;
    #pragma unroll
    for (int e = 0; e < 8; ++e) p[e] += h * (double)wp[e];
  }
  #pragma unroll
  for (int e = 0; e < 8; ++e)
    for (int off = 32; off > 0; off >>= 1)
      p[e] += __shfl_down(p[e], off);
  __shared__ double sp[4][8];
  const int lane = threadIdx.x & 63, wv = threadIdx.x >> 6;
  if (lane == 0) {
    #pragma unroll
    for (int e = 0; e < 8; ++e) sp[wv][e] = p[e];
  }
  __syncthreads();
  if (threadIdx.x == 0) {
    float l[8];
    #pragma unroll
    for (int e = 0; e < 8; ++e)
      l[e] = (float)(sp[0][e] + sp[1][e] + sp[2][e] + sp[3][e] + (double)b3[e]);
    float mx = l[0];
    for (int e = 1; e < 8; ++e) mx = fmaxf(mx, l[e]);
    float ex[8], s = 0.f;
    for (int e = 0; e < 8; ++e) { ex[e] = expf(l[e] - mx); s += ex[e]; }
    float p1 = -1.f, p2 = -1.f; int e1 = 0, e2 = 0;
    for (int e = 0; e < 8; ++e) {
      const float pe = ex[e] / s;
      if (pe > p1)      { p2 = p1; e2 = e1; p1 = pe; e1 = e; }
      else if (pe > p2) { p2 = pe; e2 = e; }
    }
    const int tok = flags[srow];
    eidx[tok * 2] = e1; eidx[tok * 2 + 1] = e2;
    gval[tok * 2] = p1; gval[tok * 2 + 1] = p2;
  }
}

// ---------------------------------------------------------------------------
// FCFS capacity scan: one wave per (expert, batch-row); exact cumsum semantics.
// Builds rowsrc (slot->token, FULLY initialized incl. -1 tail) and tokslot.
// ---------------------------------------------------------------------------
__global__ void route_scan(const int* __restrict__ eidx, const float* __restrict__ gval,
                           int* __restrict__ cnt, int* __restrict__ rowsrc,
                           int* __restrict__ tokslot)
{
  const int pair = blockIdx.x;            // e*8 + b
  const int e = pair >> 3, b = pair & 7;
  const int lane = threadIdx.x;           // blockDim = 64
  int running = 0;
  for (int t0 = 0; t0 < 2048; t0 += 64) {
    const int t = t0 + lane;
    const int i2 = (b * 2048 + t) * 2;
    const int m0 = (eidx[i2] == e), m1 = (eidx[i2 + 1] == e);
    const int m = m0 | m1;
    const unsigned long long bal = __ballot(m);
    const int pos = running + __popcll(bal & ((1ull << lane) - 1ull));
    if (m && pos < 320) {
      const int slot = pair * 320 + pos;
      rowsrc[slot] = b * 2048 + t;
      tokslot[(b * 2048 + t) * 2 + (m0 ? 0 : 1)] = slot;
    }
    running += __popcll(bal);
  }
  const int c = running < 320 ? running : 320;
  for (int s = c + lane; s < 320; s += 64) rowsrc[pair * 320 + s] = -1;
  if (lane == 0) cnt[pair] = c;
}

// ---------------------------------------------------------------------------
// Combine: out[token] = sum_j gate_j * yb[slot_j]  (bias already in yb)
// ---------------------------------------------------------------------------
__global__ void combine(const f16* __restrict__ yb, const int* __restrict__ tokslot,
                        const float* __restrict__ gval, float* __restrict__ out)
{
  const int t = blockIdx.x;
  const int s0 = tokslot[t * 2], s1 = tokslot[t * 2 + 1];
  const float g0 = gval[t * 2], g1 = gval[t * 2 + 1];
  float a[8] = {};
  if (s0 >= 0) {
    const half8 y = ((const half8*)(yb + (size_t)s0 * 1024))[threadIdx.x];
    #pragma unroll
    for (int k = 0; k < 8; ++k) a[k] += g0 * (float)y[k];
  }
  if (s1 >= 0) {
    const half8 y = ((const half8*)(yb + (size_t)s1 * 1024))[threadIdx.x];
    #pragma unroll
    for (int k = 0; k < 8; ++k) a[k] += g1 * (float)y[k];
  }
  float* dst = out + (size_t)t * 1024 + threadIdx.x * 8;
  f32x4 lo = { a[0], a[1], a[2], a[3] }, hi = { a[4], a[5], a[6], a[7] };
  *(f32x4*)dst = lo;
  *(f32x4*)(dst + 4) = hi;
}

// ---------------------------------------------------------------------------
extern "C" void kernel_launch(void* const* d_in, const int* in_sizes, int n_in,
                              void* d_out, int out_size, void* d_ws, size_t ws_size,
                              hipStream_t stream)
{
  (void)in_sizes; (void)n_in; (void)out_size;
  const float* x   = (const float*)d_in[0];
  const float* rw1 = (const float*)d_in[1];
  const float* rb1 = (const float*)d_in[2];
  const float* rw2 = (const float*)d_in[3];
  const float* rb2 = (const float*)d_in[4];
  const float* rw3 = (const float*)d_in[5];
  const float* rb3 = (const float*)d_in[6];
  const float* ew1 = (const float*)d_in[7];
  const float* eb1 = (const float*)d_in[8];
  const float* ew2 = (const float*)d_in[9];
  const float* eb2 = (const float*)d_in[10];

  constexpr size_t MB = 1024ull * 1024ull;
  constexpr size_t KB = 1024ull;
  char* ws = (char*)d_ws;
  if (ws_size < 401 * MB) return;   // need 401 MB of scratch

  // --- region 0..128 MB: router phase = h1f [16384][4096] f16;
  //     expert phase = ew1t(64) + ew2t(64)  (transposes run after router)
  f16*   h1f  = (f16*)(ws);
  f16*   ew1t = (f16*)(ws);
  f16*   ew2t = (f16*)(ws + 64 * MB);
  // --- persistent
  f16*   xhi  = (f16*)(ws + 128 * MB);               // 32MB [16384][1024]
  char*  S    = ws + 160 * MB;                       // small arrays (1MB)
  int*   eidx   = (int*)(S);                         // 128KB
  float* gval   = (float*)(S + 128 * KB);            // 128KB
  int*   cnt    = (int*)(S + 256 * KB);              // 256B
  int*   nfc    = (int*)(S + 260 * KB);              // 4B
  int*   flags  = (int*)(S + 264 * KB);              // 8KB
  int*   tokslot= (int*)(S + 272 * KB);              // 128KB
  int*   rowsrc = (int*)(S + 400 * KB);              // 80KB
  f16*   zeros  = (f16*)(S + 480 * KB);              // 16KB
  // --- router phase (161..305)
  f16*   xlo    = (f16*)(ws + 161 * MB);             // 32MB
  f16*   rw1thi = (f16*)(ws + 193 * MB);             // 8MB  [H][C]
  f16*   rw1tlo = (f16*)(ws + 201 * MB);             // 8MB
  f16*   rw2thi = (f16*)(ws + 209 * MB);             // 32MB [H][H]
  f16*   rw2tlo = (f16*)(ws + 241 * MB);             // 32MB
  float* part   = (float*)(ws + 273 * MB);           // 32MB [64][16384][8]
  // --- recompute (305..401; xlo/rw*t still live; part dead)
  float* h1r    = (float*)(ws + 305 * MB);           // 32MB [2048][4096] f32
  float* h2r    = (float*)(ws + 337 * MB);           // 32MB
  f16*   h1rh   = (f16*)(ws + 369 * MB);             // 16MB
  f16*   h1rl   = (f16*)(ws + 385 * MB);             // 16MB -> 401
  // --- expert phase (everything above 161 dead)
  f16*   h_e    = (f16*)(ws + 161 * MB);             // 160MB [20480][4096]
  f16*   yb     = (f16*)(ws + 321 * MB);             // 40MB  [20480][1024]

  // init
  hipMemsetAsync(nfc, 0, 4, stream);
  hipMemsetAsync(tokslot, 0xFF, 128 * KB, stream);
  hipMemsetAsync(zeros, 0, 16 * KB, stream);
  hipMemsetAsync(h1r, 0, 64 * MB, stream);           // h1r+h2r contiguous

  // conversions / splits (router weights only; expert weights later)
  split_x<<<8192, 256, 0, stream>>>(x, xhi, xlo, 16384 * 1024);
  transpose_conv<true ><<<dim3(64, 16, 1), 256, 0, stream>>>(rw1, rw1thi, rw1tlo, 1024, 4096);
  transpose_conv<true ><<<dim3(64, 64, 1), 256, 0, stream>>>(rw2, rw2thi, rw2tlo, 4096, 4096);

  // FAST router: plain f16, ALL 16384 tokens in one pass
  gemm256<0, false><<<dim3(16, 64), 512, 0, stream>>>(
      xhi, nullptr, rw1thi, nullptr, 4096, 1024, 1024, 1024,
      nullptr, nullptr, rb1, 0, 0,
      h1f, 4096, nullptr, nullptr, nullptr, nullptr);
  gemm256<2, false><<<dim3(16, 64), 512, 0, stream>>>(
      h1f, nullptr, rw2thi, nullptr, 4096, 4096, 4096, 4096,
      nullptr, nullptr, rb2, 0, 0,
      nullptr, 16384, nullptr, rw3, part, nullptr);
  topk_flag<<<64, 256, 0, stream>>>(part, rb3, eidx, gval, flags, nfc);

  // EXACT recompute for flagged tokens (split-K f32-atomic, f16x3 split)
  gemm256<3, true><<<dim3(16, 8, 2), 512, 0, stream>>>(
      xhi, xlo, rw1thi, rw1tlo, 4096, 512, 1024, 1024,
      flags, zeros, nullptr, 0, 0,
      nullptr, 4096, h1r, nullptr, nullptr, nfc);
  post1<<<dim3(2048, 2), 256, 0, stream>>>(h1r, rb1, h1rh, h1rl, nfc);
  gemm256<3, true><<<dim3(16, 8, 4), 512, 0, stream>>>(
      h1rh, h1rl, rw2thi, rw2tlo, 4096, 1024, 4096, 4096,
      nullptr, nullptr, nullptr, 0, 0,
      nullptr, 4096, h2r, nullptr, nullptr, nfc);
  logits_exact<<<NF_MAX, 256, 0, stream>>>(h2r, rb2, rw3, rb3, flags, nfc,
                                           eidx, gval);

  // dispatch maps
  route_scan<<<64, 64, 0, stream>>>(eidx, gval, cnt, rowsrc, tokslot);

  // expert weight conversion (h1f region now dead)
  transpose_conv<false><<<dim3(64, 16, 8), 256, 0, stream>>>(ew1, ew1t, nullptr, 1024, 4096);
  transpose_conv<false><<<dim3(16, 64, 8), 256, 0, stream>>>(ew2, ew2t, nullptr, 4096, 1024);

  // experts: A-rows gathered by indirection from xhi (zero page for empties)
  gemm256<0, false><<<dim3(16, 80), 512, 0, stream>>>(
      xhi, nullptr, ew1t, nullptr, 4096, 1024, 1024, 1024,
      rowsrc, zeros, eb1, 4096, 2560,
      h_e, 4096, nullptr, nullptr, nullptr, nullptr);
  gemm256<1, false><<<dim3(4, 80), 512, 0, stream>>>(
      h_e, nullptr, ew2t, nullptr, 1024, 4096, 4096, 4096,
      nullptr, nullptr, eb2, 1024, 2560,
      yb, 1024, nullptr, nullptr, nullptr, nullptr);

  // combine: one write per output element (dropped tokens -> 0)
  combine<<<16384, 128, 0, stream>>>(yb, tokslot, gval, (float*)d_out);
}

// Round 10
// 1764.807 us; speedup vs baseline: 1.4709x; 1.0125x over previous
//
#include <hip/hip_runtime.h>
#include <stdint.h>

typedef _Float16 f16;
typedef _Float16 half8 __attribute__((ext_vector_type(8)));
typedef float f32x4 __attribute__((ext_vector_type(4)));

// ---------------------------------------------------------------------------
// MoE constants: B=8, T=2048, C=1024, H=4096, E=8, K=2, CAP=320
// tokens M=16384, expert slots = 20480, rows/expert = 2560
// Router: plain-f16 pipeline + fused logits epilogue (partial stores, no
// atomics); tokens with sorted logit gap l(2)-l(3) < THETA get exact
// (f16x3 split, split-K atomic) recompute -> top-2 SET / cumsum exact.
// GEMM: 256x256 tile, BK=64, 8 waves, 4-phase pipelined K-loop.
// NEW (r10): per-XCD 4x8 SUPERTILE block mapping — each XCD's 32 concurrent
// blocks cover a 4-row x 8-col tile region (perimeter 12 tiles = 384 KB
// unique per K-step vs 576 KB for the old 2x16 region) -> 1.5x less L3->L2
// traffic on the L3-BW-bound router/expert GEMMs.
// ---------------------------------------------------------------------------
#define NF_MAX 2048
#define THETA  0.02f

__device__ __forceinline__ void gload16(const void* g, void* l) {
  __builtin_amdgcn_global_load_lds(
      (const __attribute__((address_space(1))) void*)g,
      (__attribute__((address_space(3))) void*)l, 16, 0, 0);
}

#define BAR() do { __builtin_amdgcn_s_barrier(); __builtin_amdgcn_sched_barrier(0); } while (0)
#define WAIT_VM8() do { asm volatile("s_waitcnt vmcnt(8)" ::: "memory"); __builtin_amdgcn_sched_barrier(0); } while (0)
#define WAIT_VM0() do { asm volatile("s_waitcnt vmcnt(0)" ::: "memory"); __builtin_amdgcn_sched_barrier(0); } while (0)

// ---------------------------------------------------------------------------
// 256x256-tile f16 MFMA GEMM, 8 waves (2Mx4N), BK=64, 4-phase pipelined
// K-loop (round-4 form; ring of 4 kc-half slots/operand, fragment-major LDS,
// conflict-free lane-linear ds_read_b128, counted vmcnt(8), raw s_barrier,
// setprio around MFMA).
// Block mapping: hardware assigns linear bid -> XCD = bid&7. We map the
// j-th block of XCD x (j = bid>>3) into 4x8 supertiles: round r = j>>5 picks
// supertile s = r*8+x; jp = j&31 walks the 4x8 tiles inside. Bijective when
// gx%8==0, gy%4==0, ((gx/8)*(gy/4))%8==0; otherwise falls back to the
// proven bid%8-chunk swizzle (requires (gx*gy)%8==0 — true for all grids).
//  A: [M][lda] f16 row-major (optional rowsrcA indirection; <0 -> zeroPage).
//  B N-major: [N][ldb] f16. Split-K: grid.z chunks of Kd, k0 = z*Kd.
//  SPLIT3: A=A0+2^-12*A1, B=B0+2^-12*B1 (lo pre-scaled x4096); 3 K-passes.
//  EPI: 0 relu + f16 store (oH)
//       1 bias + f16 store, no relu (oH)
//       2 fused logits: relu, dot w3[4096][8], 16-lane shfl reduce, plain
//         store partial -> oLog[(n0>>8)*4+wn][row][8] (row stride = ldo)
//       3 raw f32 atomicAdd partials into oAcc (no bias)
//  nfp: blocks with m0 >= pad256(min(*nfp,NF_MAX)) exit immediately.
// ---------------------------------------------------------------------------
template<int EPI, bool SPLIT3>
__launch_bounds__(512, 2)
__global__ void gemm256(const f16* __restrict__ A0, const f16* __restrict__ A1,
                        const f16* __restrict__ B0, const f16* __restrict__ B1,
                        int N, int Kd, int lda, int ldb,
                        const int* __restrict__ rowsrcA, const f16* __restrict__ zeroPage,
                        const float* __restrict__ bias, int bias_stride, int rows_per_exp,
                        f16* __restrict__ oH, int ldo, float* __restrict__ oAcc,
                        const float* __restrict__ w3, float* __restrict__ oLog,
                        const int* __restrict__ nfp)
{
  __shared__ f16 lds[4 * 8192 * 2 + 512];     // A ring | B ring | 1KB dummy
  f16* sA = lds;
  f16* sB = lds + 4 * 8192;
  f16* sDummy = lds + 8 * 8192;

  const int tid  = threadIdx.x;
  const int lane = tid & 63, w = tid >> 6;    // 8 waves
  const int wm = w >> 2, wn = w & 3;          // 2 x 4 wave grid

  // block -> tile mapping (see header comment)
  const int gx  = gridDim.x, gy = gridDim.y;
  const int bid = blockIdx.y * gx + blockIdx.x;
  int by, bx;
  const int scols = gx >> 3;                  // supertile grid cols
  const int nst   = scols * (gy >> 2);        // supertile count
  if ((gx & 7) == 0 && (gy & 3) == 0 && (nst & 7) == 0) {
    const int x = bid & 7, j = bid >> 3;      // XCD, per-XCD sequence
    const int r = j >> 5, jp = j & 31;        // round, intra-supertile
    const int s = r * 8 + x;                  // supertile id
    const int srow = s / scols, scol = s - srow * scols;
    by = srow * 4 + (jp >> 3);
    bx = scol * 8 + (jp & 7);
  } else {
    const int nwg = gx * gy;
    const int swz = (bid & 7) * (nwg >> 3) + (bid >> 3);
    by = swz / gx; bx = swz - by * gx;
  }
  const int m0  = by * 256, n0 = bx * 256;
  const int k0  = blockIdx.z * Kd;            // split-K window base

  if (nfp) {                                  // recompute-path early exit
    int nf = *nfp; nf = nf < NF_MAX ? nf : NF_MAX;
    const int lim = (nf + 255) & ~255;
    if (m0 >= lim) return;
  }

  int e = 0;
  if (rows_per_exp > 0) e = m0 / rows_per_exp;
  const f16* Bh = B0 + (size_t)e * N * ldb;

  const int nk  = Kd >> 6;
  const int NIT = SPLIT3 ? 3 * nk : nk;

  // staging lane decode
  const int sr  = lane & 15;                  // row within 16-row tile
  const int sk8 = lane >> 4;                  // 16B column within 32-col half

  // per-thread fixed row offsets (A may be indirect)
  size_t aoff[2], boff[2];
  bool az[2] = { false, false };
  #pragma unroll
  for (int jj = 0; jj < 2; ++jj) {
    const int arow = m0 + (jj * 8 + w) * 16 + sr;
    if (rowsrcA) {
      const int rs = rowsrcA[arow];
      az[jj] = (rs < 0);
      aoff[jj] = az[jj] ? 0 : (size_t)rs * lda;
    } else {
      aoff[jj] = (size_t)arow * lda;
    }
    boff[jj] = (size_t)(n0 + (jj * 8 + w) * 16 + sr) * ldb;
  }

  auto stageA = [&](const f16* base, int kk, int kc, f16* slotBase, bool valid) {
    #pragma unroll
    for (int jj = 0; jj < 2; ++jj) {
      const int mt = jj * 8 + w;
      f16* dst = valid ? (slotBase + mt * 512) : sDummy;
      const f16* src = az[jj] ? zeroPage
                              : base + aoff[jj] + (k0 + kk + kc * 32 + sk8 * 8);
      gload16(src, dst);
    }
  };
  auto stageB = [&](const f16* base, int kk, int kc, f16* slotBase, bool valid) {
    #pragma unroll
    for (int jj = 0; jj < 2; ++jj) {
      const int mt = jj * 8 + w;
      f16* dst = valid ? (slotBase + mt * 512) : sDummy;
      const f16* src = base + boff[jj] + (k0 + kk + kc * 32 + sk8 * 8);
      gload16(src, dst);
    }
  };

  struct It { const f16* Ab; const f16* Bb; int kk, kin, pass; };
  const f16* Ab0 = SPLIT3 ? A1 : A0;
  auto advance = [&](It& s) {
    if (s.kin + 1 < nk) { s.kin++; }
    else if (SPLIT3 && s.pass < 2) {
      s.kin = 0; s.pass++;
      s.Ab = (s.pass == 0) ? A1 : A0;
      s.Bb = (s.pass == 1) ? B1 : Bh;
    } // else saturate (dest is dummy anyway)
    s.kk = s.kin << 6;
  };
  It it1 = { Ab0, Bh, 64, 1, 0 };             // j = t+1
  It it2 = { Ab0, Bh, 128, 2, 0 };            // j = t+2

  // prologue: stage (0,kc0)A/B, (0,kc1)A/B, (1,kc0)A/B -> slots 0,1,2
  stageA(Ab0, 0, 0, &sA[0], true);
  stageB(Bh,  0, 0, &sB[0], true);
  stageA(Ab0, 0, 1, &sA[8192], true);
  stageB(Bh,  0, 1, &sB[8192], true);
  stageA(it1.Ab, it1.kk, 0, &sA[2 * 8192], true);
  stageB(it1.Bb, it1.kk, 0, &sB[2 * 8192], true);
  WAIT_VM8();
  BAR();

  f32x4 acc[8][4] = {};
  const int aBase = wm * 8;
  const int bBase = wn * 4;

  auto mfma16 = [&](half8* af, half8* bf, int moff) {
    __builtin_amdgcn_s_setprio(1);
    #pragma unroll
    for (int mi = 0; mi < 4; ++mi)
      #pragma unroll
      for (int ni = 0; ni < 4; ++ni)
        acc[moff + mi][ni] = __builtin_amdgcn_mfma_f32_16x16x32_f16(
            af[mi], bf[ni], acc[moff + mi][ni], 0, 0, 0);
    __builtin_amdgcn_s_setprio(0);
  };
  auto rdA = [&](half8* dst, int slot, int mtb) {
    #pragma unroll
    for (int mi = 0; mi < 4; ++mi)
      dst[mi] = *(const half8*)&sA[slot * 8192 + (mtb + mi) * 512 + lane * 8];
  };
  auto rdB = [&](half8* dst, int slot) {
    #pragma unroll
    for (int ni = 0; ni < 4; ++ni)
      dst[ni] = *(const half8*)&sB[slot * 8192 + (bBase + ni) * 512 + lane * 8];
  };

  for (int t = 0; t < NIT; ++t) {
    const int sa0 = (2 * t) & 3, sa1 = sa0 ^ 1;
    const bool v1 = (t + 1 < NIT), v2 = (t + 2 < NIT);

    if (SPLIT3 && t == 2 * nk) {              // lo-passes done: scale 2^-12
      #pragma unroll
      for (int mi = 0; mi < 8; ++mi)
        #pragma unroll
        for (int ni = 0; ni < 4; ++ni)
          acc[mi][ni] = acc[mi][ni] * 2.44140625e-4f;
    }

    half8 aF[4], bF[4], aG[4];

    // p0: read A(mh0,kc0)+B(kc0); stage (t+1,kc1)A -> slot sa0^3
    rdA(aF, sa0, aBase);
    rdB(bF, sa0);
    stageA(it1.Ab, it1.kk, 1, &sA[(sa0 ^ 3) * 8192], v1);
    BAR();
    mfma16(aF, bF, 0);
    BAR();

    // p1: read A(mh1,kc0); stage (t+1,kc1)B; vmcnt(8) covers (t,kc1)
    rdA(aG, sa0, aBase + 4);
    stageB(it1.Bb, it1.kk, 1, &sB[(sa0 ^ 3) * 8192], v1);
    WAIT_VM8();
    BAR();
    mfma16(aG, bF, 4);
    BAR();

    // p2: read A(mh0,kc1)+B(kc1); stage (t+2,kc0)A -> slot sa0 (now dead)
    rdA(aF, sa1, aBase);
    rdB(bF, sa1);
    stageA(it2.Ab, it2.kk, 0, &sA[sa0 * 8192], v2);
    BAR();
    mfma16(aF, bF, 0);
    BAR();

    // p3: read A(mh1,kc1); stage (t+2,kc0)B; vmcnt(8) covers (t+1,kc0)
    rdA(aG, sa1, aBase + 4);
    stageB(it2.Bb, it2.kk, 0, &sB[sa0 * 8192], v2);
    WAIT_VM8();
    BAR();
    mfma16(aG, bF, 4);
    BAR();

    it1 = it2;
    advance(it2);
  }
  WAIT_VM0();   // drain tail (dummy) loads before LDS is released

  // epilogue ---------------------------------------------------------------
  float bv[4] = { 0.f, 0.f, 0.f, 0.f };
  if (bias) {
    #pragma unroll
    for (int ni = 0; ni < 4; ++ni) {
      const int col = n0 + wn * 64 + ni * 16 + (lane & 15);
      bv[ni] = bias[(size_t)e * bias_stride + col];
    }
  }

  if (EPI == 2) {
    f32x4 wlo[4], whi[4];
    #pragma unroll
    for (int ni = 0; ni < 4; ++ni) {
      const int col = n0 + wn * 64 + ni * 16 + (lane & 15);
      wlo[ni] = *(const f32x4*)(w3 + (size_t)col * 8);
      whi[ni] = *(const f32x4*)(w3 + (size_t)col * 8 + 4);
    }
    const int p = (n0 >> 8) * 4 + wn;           // 0..63, private slot
    #pragma unroll
    for (int mi = 0; mi < 8; ++mi) {
      #pragma unroll
      for (int r = 0; r < 4; ++r) {
        const int row = m0 + wm * 128 + mi * 16 + (lane >> 4) * 4 + r;
        f32x4 plo = {}, phi = {};
        #pragma unroll
        for (int ni = 0; ni < 4; ++ni) {
          const float v = fmaxf(acc[mi][ni][r] + bv[ni], 0.f);
          plo += v * wlo[ni];
          phi += v * whi[ni];
        }
        #pragma unroll
        for (int msk = 1; msk < 16; msk <<= 1) {
          #pragma unroll
          for (int q = 0; q < 4; ++q) {
            plo[q] += __shfl_xor(plo[q], msk);
            phi[q] += __shfl_xor(phi[q], msk);
          }
        }
        if ((lane & 15) == 0) {
          float* dst = oLog + ((size_t)p * ldo + row) * 8;
          *(f32x4*)dst = plo;
          *(f32x4*)(dst + 4) = phi;
        }
      }
    }
  } else {
    #pragma unroll
    for (int mi = 0; mi < 8; ++mi) {
      #pragma unroll
      for (int r = 0; r < 4; ++r) {
        const int row = m0 + wm * 128 + mi * 16 + (lane >> 4) * 4 + r;
        #pragma unroll
        for (int ni = 0; ni < 4; ++ni) {
          const int col = n0 + wn * 64 + ni * 16 + (lane & 15);
          if (EPI == 3) {
            atomicAdd(&oAcc[(size_t)row * ldo + col], acc[mi][ni][r]);
          } else {
            float v = acc[mi][ni][r] + bv[ni];
            if (EPI == 0) v = fmaxf(v, 0.f);
            oH[(size_t)row * ldo + col] = (f16)v;
          }
        }
      }
    }
  }
}

// ---------------------------------------------------------------------------
// x (f32) -> hi f16 + lo f16 (x4096), 8 elems/thread
// ---------------------------------------------------------------------------
__global__ void split_x(const float* __restrict__ x, f16* __restrict__ hi,
                        f16* __restrict__ lo, int n)
{
  const int i = blockIdx.x * 256 + threadIdx.x;
  if (i * 8 >= n) return;
  const f32x4 a = ((const f32x4*)x)[2 * i];
  const f32x4 b = ((const f32x4*)x)[2 * i + 1];
  half8 h, l;
  #pragma unroll
  for (int j = 0; j < 4; ++j) {
    float v = a[j]; f16 hh = (f16)v;
    h[j] = hh; l[j] = (f16)((v - (float)hh) * 4096.0f);
    v = b[j]; hh = (f16)v;
    h[4 + j] = hh; l[4 + j] = (f16)((v - (float)hh) * 4096.0f);
  }
  ((half8*)hi)[i] = h;
  ((half8*)lo)[i] = l;
}

// ---------------------------------------------------------------------------
// Transpose-convert: in f32 [R][Cc] -> out f16 [Cc][R] (optional split lo)
// ---------------------------------------------------------------------------
template<bool SPLIT>
__global__ void transpose_conv(const float* __restrict__ in, f16* __restrict__ oh,
                               f16* __restrict__ ol, int R, int Cc)
{
  __shared__ float tile[64][65];
  const size_t boff = (size_t)blockIdx.z * R * Cc;
  in += boff; oh += boff;
  if (SPLIT) ol += boff;
  const int c0 = blockIdx.x * 64, r0 = blockIdx.y * 64;
  #pragma unroll
  for (int i = 0; i < 16; ++i) {
    const int idx = i * 256 + threadIdx.x;
    const int r = idx >> 6, c = idx & 63;
    tile[r][c] = in[(size_t)(r0 + r) * Cc + (c0 + c)];
  }
  __syncthreads();
  #pragma unroll
  for (int i = 0; i < 16; ++i) {
    const int idx = i * 256 + threadIdx.x;
    const int ro = idx >> 6, co = idx & 63;
    const float v = tile[co][ro];
    const f16 h = (f16)v;
    const size_t o = (size_t)(c0 + ro) * R + (r0 + co);
    oh[o] = h;
    if (SPLIT) ol[o] = (f16)((v - (float)h) * 4096.0f);
  }
}

// ---------------------------------------------------------------------------
// softmax + top-2 + margin flagging; sums 64 per-(block,wave) partials
// ---------------------------------------------------------------------------
__global__ void topk_flag(const float* __restrict__ part, const float* __restrict__ b3,
                          int* __restrict__ eidx, float* __restrict__ gval,
                          int* __restrict__ flags, int* __restrict__ nfc)
{
  const int t = blockIdx.x * 256 + threadIdx.x;     // 0..16383
  float l[8];
  #pragma unroll
  for (int e = 0; e < 8; ++e) l[e] = b3[e];
  for (int p = 0; p < 64; ++p) {
    const float* src = part + ((size_t)p * 16384 + t) * 8;
    const f32x4 a = *(const f32x4*)src;
    const f32x4 b = *(const f32x4*)(src + 4);
    #pragma unroll
    for (int q = 0; q < 4; ++q) { l[q] += a[q]; l[4 + q] += b[q]; }
  }
  float mx = l[0];
  #pragma unroll
  for (int e = 1; e < 8; ++e) mx = fmaxf(mx, l[e]);
  float ex[8], s = 0.f;
  #pragma unroll
  for (int e = 0; e < 8; ++e) { ex[e] = expf(l[e] - mx); s += ex[e]; }
  float p1 = -1.f, p2 = -1.f; int e1 = 0, e2 = 0;
  #pragma unroll
  for (int e = 0; e < 8; ++e) {               // strict '>' = lax.top_k tie-break
    const float pe = ex[e] / s;
    if (pe > p1)      { p2 = p1; e2 = e1; p1 = pe; e1 = e; }
    else if (pe > p2) { p2 = pe; e2 = e; }
  }
  eidx[t * 2] = e1; eidx[t * 2 + 1] = e2;
  gval[t * 2] = p1; gval[t * 2 + 1] = p2;
  // sorted-logit top-3 gap -> flag for exact recompute
  float l1 = -1e30f, l2 = -1e30f, l3 = -1e30f;
  #pragma unroll
  for (int e = 0; e < 8; ++e) {
    const float le = l[e];
    if (le > l1)      { l3 = l2; l2 = l1; l1 = le; }
    else if (le > l2) { l3 = l2; l2 = le; }
    else if (le > l3) { l3 = le; }
  }
  if (l2 - l3 < THETA) {
    const int s0 = atomicAdd(nfc, 1);
    if (s0 < NF_MAX) flags[s0] = t;
  }
}

// ---------------------------------------------------------------------------
// relu(h1r + b1) -> split f16 hi/lo  (recompute path, rows < pad(nf))
// ---------------------------------------------------------------------------
__global__ void post1(const float* __restrict__ h1r, const float* __restrict__ b1,
                      f16* __restrict__ hh, f16* __restrict__ hl,
                      const int* __restrict__ nfc)
{
  int nf = *nfc; nf = nf < NF_MAX ? nf : NF_MAX;
  const int lim = (nf + 255) & ~255;
  const int row = blockIdx.x;
  if (row >= lim) return;
  const int j = blockIdx.y * 2048 + threadIdx.x * 8;
  const float* src = h1r + (size_t)row * 4096 + j;
  const f32x4 a = *(const f32x4*)src;
  const f32x4 b = *(const f32x4*)(src + 4);
  half8 h, l;
  #pragma unroll
  for (int k = 0; k < 4; ++k) {
    float v = fmaxf(a[k] + b1[j + k], 0.f);
    f16 x = (f16)v; h[k] = x; l[k] = (f16)((v - (float)x) * 4096.0f);
    v = fmaxf(b[k] + b1[j + 4 + k], 0.f);
    x = (f16)v; h[4 + k] = x; l[4 + k] = (f16)((v - (float)x) * 4096.0f);
  }
  *(half8*)(hh + (size_t)row * 4096 + j) = h;
  *(half8*)(hl + (size_t)row * 4096 + j) = l;
}

// ---------------------------------------------------------------------------
// EXACT logits for flagged tokens from f32 h2r (+b2, relu), f64 accumulate
// ---------------------------------------------------------------------------
__global__ void logits_exact(const float* __restrict__ h2r, const float* __restrict__ b2,
                             const float* __restrict__ w3, const float* __restrict__ b3,
                             const int* __restrict__ flags, const int* __restrict__ nfc,
                             int* __restrict__ eidx, float* __restrict__ gval)
{
  const int srow = blockIdx.x;
  int nf = *nfc; nf = nf < NF_MAX ? nf : NF_MAX;
  if (srow >= nf) return;
  const float* hrow = h2r + (size_t)srow * 4096;
  double p[8];
  #pragma unroll
  for (int e = 0; e < 8; ++e) p[e] = 0.0;
  for (int i = 0; i < 16; ++i) {
    const int k = i * 256 + threadIdx.x;
    const double h = (double)fmaxf(hrow[k] + b2[k], 0.f);
    const float* wp = w3 + (size_t)k * 8;
    #pragma unroll
    for (int e = 0; e < 8; ++e) p[e] += h * (double)wp[e];
  }
  #pragma unroll
  for (int e = 0; e < 8; ++e)
    for (int off = 32; off > 0; off >>= 1)
      p[e] += __shfl_down(p[e], off);
  __shared__ double sp[4][8];
  const int lane = threadIdx.x & 63, wv = threadIdx.x >> 6;
  if (lane == 0) {
    #pragma unroll
    for (int e = 0; e < 8; ++e) sp[wv][e] = p[e];
  }
  __syncthreads();
  if (threadIdx.x == 0) {
    float l[8];
    #pragma unroll
    for (int e = 0; e < 8; ++e)
      l[e] = (float)(sp[0][e] + sp[1][e] + sp[2][e] + sp[3][e] + (double)b3[e]);
    float mx = l[0];
    for (int e = 1; e < 8; ++e) mx = fmaxf(mx, l[e]);
    float ex[8], s = 0.f;
    for (int e = 0; e < 8; ++e) { ex[e] = expf(l[e] - mx); s += ex[e]; }
    float p1 = -1.f, p2 = -1.f; int e1 = 0, e2 = 0;
    for (int e = 0; e < 8; ++e) {
      const float pe = ex[e] / s;
      if (pe > p1)      { p2 = p1; e2 = e1; p1 = pe; e1 = e; }
      else if (pe > p2) { p2 = pe; e2 = e; }
    }
    const int tok = flags[srow];
    eidx[tok * 2] = e1; eidx[tok * 2 + 1] = e2;
    gval[tok * 2] = p1; gval[tok * 2 + 1] = p2;
  }
}

// ---------------------------------------------------------------------------
// FCFS capacity scan: one wave per (expert, batch-row); exact cumsum semantics.
// Builds rowsrc (slot->token, FULLY initialized incl. -1 tail) and tokslot.
// ---------------------------------------------------------------------------
__global__ void route_scan(const int* __restrict__ eidx, const float* __restrict__ gval,
                           int* __restrict__ cnt, int* __restrict__ rowsrc,
                           int* __restrict__ tokslot)
{
  const int pair = blockIdx.x;            // e*8 + b
  const int e = pair >> 3, b = pair & 7;
  const int lane = threadIdx.x;           // blockDim = 64
  int running = 0;
  for (int t0 = 0; t0 < 2048; t0 += 64) {
    const int t = t0 + lane;
    const int i2 = (b * 2048 + t) * 2;
    const int m0 = (eidx[i2] == e), m1 = (eidx[i2 + 1] == e);
    const int m = m0 | m1;
    const unsigned long long bal = __ballot(m);
    const int pos = running + __popcll(bal & ((1ull << lane) - 1ull));
    if (m && pos < 320) {
      const int slot = pair * 320 + pos;
      rowsrc[slot] = b * 2048 + t;
      tokslot[(b * 2048 + t) * 2 + (m0 ? 0 : 1)] = slot;
    }
    running += __popcll(bal);
  }
  const int c = running < 320 ? running : 320;
  for (int s = c + lane; s < 320; s += 64) rowsrc[pair * 320 + s] = -1;
  if (lane == 0) cnt[pair] = c;
}

// ---------------------------------------------------------------------------
// Combine: out[token] = sum_j gate_j * yb[slot_j]  (bias already in yb)
// ---------------------------------------------------------------------------
__global__ void combine(const f16* __restrict__ yb, const int* __restrict__ tokslot,
                        const float* __restrict__ gval, float* __restrict__ out)
{
  const int t = blockIdx.x;
  const int s0 = tokslot[t * 2], s1 = tokslot[t * 2 + 1];
  const float g0 = gval[t * 2], g1 = gval[t * 2 + 1];
  float a[8] = {};
  if (s0 >= 0) {
    const half8 y = ((const half8*)(yb + (size_t)s0 * 1024))[threadIdx.x];
    #pragma unroll
    for (int k = 0; k < 8; ++k) a[k] += g0 * (float)y[k];
  }
  if (s1 >= 0) {
    const half8 y = ((const half8*)(yb + (size_t)s1 * 1024))[threadIdx.x];
    #pragma unroll
    for (int k = 0; k < 8; ++k) a[k] += g1 * (float)y[k];
  }
  float* dst = out + (size_t)t * 1024 + threadIdx.x * 8;
  f32x4 lo = { a[0], a[1], a[2], a[3] }, hi = { a[4], a[5], a[6], a[7] };
  *(f32x4*)dst = lo;
  *(f32x4*)(dst + 4) = hi;
}

// ---------------------------------------------------------------------------
extern "C" void kernel_launch(void* const* d_in, const int* in_sizes, int n_in,
                              void* d_out, int out_size, void* d_ws, size_t ws_size,
                              hipStream_t stream)
{
  (void)in_sizes; (void)n_in; (void)out_size;
  const float* x   = (const float*)d_in[0];
  const float* rw1 = (const float*)d_in[1];
  const float* rb1 = (const float*)d_in[2];
  const float* rw2 = (const float*)d_in[3];
  const float* rb2 = (const float*)d_in[4];
  const float* rw3 = (const float*)d_in[5];
  const float* rb3 = (const float*)d_in[6];
  const float* ew1 = (const float*)d_in[7];
  const float* eb1 = (const float*)d_in[8];
  const float* ew2 = (const float*)d_in[9];
  const float* eb2 = (const float*)d_in[10];

  constexpr size_t MB = 1024ull * 1024ull;
  constexpr size_t KB = 1024ull;
  char* ws = (char*)d_ws;
  if (ws_size < 401 * MB) return;   // need 401 MB of scratch

  // --- region 0..128 MB: router phase = h1f [16384][4096] f16;
  //     expert phase = ew1t(64) + ew2t(64)  (transposes run after router)
  f16*   h1f  = (f16*)(ws);
  f16*   ew1t = (f16*)(ws);
  f16*   ew2t = (f16*)(ws + 64 * MB);
  // --- persistent
  f16*   xhi  = (f16*)(ws + 128 * MB);               // 32MB [16384][1024]
  char*  S    = ws + 160 * MB;                       // small arrays (1MB)
  int*   eidx   = (int*)(S);                         // 128KB
  float* gval   = (float*)(S + 128 * KB);            // 128KB
  int*   cnt    = (int*)(S + 256 * KB);              // 256B
  int*   nfc    = (int*)(S + 260 * KB);              // 4B
  int*   flags  = (int*)(S + 264 * KB);              // 8KB
  int*   tokslot= (int*)(S + 272 * KB);              // 128KB
  int*   rowsrc = (int*)(S + 400 * KB);              // 80KB
  f16*   zeros  = (f16*)(S + 480 * KB);              // 16KB
  // --- router phase (161..305)
  f16*   xlo    = (f16*)(ws + 161 * MB);             // 32MB
  f16*   rw1thi = (f16*)(ws + 193 * MB);             // 8MB  [H][C]
  f16*   rw1tlo = (f16*)(ws + 201 * MB);             // 8MB
  f16*   rw2thi = (f16*)(ws + 209 * MB);             // 32MB [H][H]
  f16*   rw2tlo = (f16*)(ws + 241 * MB);             // 32MB
  float* part   = (float*)(ws + 273 * MB);           // 32MB [64][16384][8]
  // --- recompute (305..401; xlo/rw*t still live; part dead)
  float* h1r    = (float*)(ws + 305 * MB);           // 32MB [2048][4096] f32
  float* h2r    = (float*)(ws + 337 * MB);           // 32MB
  f16*   h1rh   = (f16*)(ws + 369 * MB);             // 16MB
  f16*   h1rl   = (f16*)(ws + 385 * MB);             // 16MB -> 401
  // --- expert phase (everything above 161 dead)
  f16*   h_e    = (f16*)(ws + 161 * MB);             // 160MB [20480][4096]
  f16*   yb     = (f16*)(ws + 321 * MB);             // 40MB  [20480][1024]

  // init
  hipMemsetAsync(nfc, 0, 4, stream);
  hipMemsetAsync(tokslot, 0xFF, 128 * KB, stream);
  hipMemsetAsync(zeros, 0, 16 * KB, stream);
  hipMemsetAsync(h1r, 0, 64 * MB, stream);           // h1r+h2r contiguous

  // conversions / splits (router weights only; expert weights later)
  split_x<<<8192, 256, 0, stream>>>(x, xhi, xlo, 16384 * 1024);
  transpose_conv<true ><<<dim3(64, 16, 1), 256, 0, stream>>>(rw1, rw1thi, rw1tlo, 1024, 4096);
  transpose_conv<true ><<<dim3(64, 64, 1), 256, 0, stream>>>(rw2, rw2thi, rw2tlo, 4096, 4096);

  // FAST router: plain f16, ALL 16384 tokens in one pass
  gemm256<0, false><<<dim3(16, 64), 512, 0, stream>>>(
      xhi, nullptr, rw1thi, nullptr, 4096, 1024, 1024, 1024,
      nullptr, nullptr, rb1, 0, 0,
      h1f, 4096, nullptr, nullptr, nullptr, nullptr);
  gemm256<2, false><<<dim3(16, 64), 512, 0, stream>>>(
      h1f, nullptr, rw2thi, nullptr, 4096, 4096, 4096, 4096,
      nullptr, nullptr, rb2, 0, 0,
      nullptr, 16384, nullptr, rw3, part, nullptr);
  topk_flag<<<64, 256, 0, stream>>>(part, rb3, eidx, gval, flags, nfc);

  // EXACT recompute for flagged tokens (split-K f32-atomic, f16x3 split)
  gemm256<3, true><<<dim3(16, 8, 2), 512, 0, stream>>>(
      xhi, xlo, rw1thi, rw1tlo, 4096, 512, 1024, 1024,
      flags, zeros, nullptr, 0, 0,
      nullptr, 4096, h1r, nullptr, nullptr, nfc);
  post1<<<dim3(2048, 2), 256, 0, stream>>>(h1r, rb1, h1rh, h1rl, nfc);
  gemm256<3, true><<<dim3(16, 8, 4), 512, 0, stream>>>(
      h1rh, h1rl, rw2thi, rw2tlo, 4096, 1024, 4096, 4096,
      nullptr, nullptr, nullptr, 0, 0,
      nullptr, 4096, h2r, nullptr, nullptr, nfc);
  logits_exact<<<NF_MAX, 256, 0, stream>>>(h2r, rb2, rw3, rb3, flags, nfc,
                                           eidx, gval);

  // dispatch maps
  route_scan<<<64, 64, 0, stream>>>(eidx, gval, cnt, rowsrc, tokslot);

  // expert weight conversion (h1f region now dead)
  transpose_conv<false><<<dim3(64, 16, 8), 256, 0, stream>>>(ew1, ew1t, nullptr, 1024, 4096);
  transpose_conv<false><<<dim3(16, 64, 8), 256, 0, stream>>>(ew2, ew2t, nullptr, 4096, 1024);

  // experts: A-rows gathered by indirection from xhi (zero page for empties)
  gemm256<0, false><<<dim3(16, 80), 512, 0, stream>>>(
      xhi, nullptr, ew1t, nullptr, 4096, 1024, 1024, 1024,
      rowsrc, zeros, eb1, 4096, 2560,
      h_e, 4096, nullptr, nullptr, nullptr, nullptr);
  gemm256<1, false><<<dim3(4, 80), 512, 0, stream>>>(
      h_e, nullptr, ew2t, nullptr, 1024, 4096, 4096, 4096,
      nullptr, nullptr, eb2, 1024, 2560,
      yb, 1024, nullptr, nullptr, nullptr, nullptr);

  // combine: one write per output element (dropped tokens -> 0)
  combine<<<16384, 128, 0, stream>>>(yb, tokslot, gval, (float*)d_out);
}